// Round 20
// baseline (157.788 us; speedup 1.0000x reference)
//
#include <hip/hip_runtime.h>
#include <stdint.h>

// Problem constants (match reference)
#define NV1 200000
#define NLM 50000
#define NTOT 250000        // NV1 + NLM
#define TLEN 600
#define UU 10
#define NNZV1 800000
#define NNZLM 200000
#define NNZTOT (NNZV1 + NNZLM)
#define NELEM (TLEN * UU)  // 6000 poisson elements

// Binning parameters (1024-row bins, R18 geometry)
#define BINSHIFT 10
#define BINROWS 1024
#define NB 245                   // ceil(250000/1024)
#define CAP 4608                 // mean 4096, sigma ~64 -> +8 sigma
#define BBLK 1024                // R20: 4 blocks/CU (was 512)
#define BPT 4                    // 1024*256*4 = 1,048,576 >= 1e6

#define THALF (TLEN / 2)         // 300

// Sort-path workspace offsets
#define SLOTS_OFF   0ULL                  // 245*4608*8 = 9,031,680 B
#define SPIKES2_OFF 9031680ULL            // 600*12*4 = 28,800 B (padded rows)
#define BINCNT_OFF  9060480ULL            // 245*4
#define WS_NEED_SORT 9061460ULL
// Fallback offsets (R6 path)
#define WT_OFF      0ULL
#define SPIKES_OFF  10000000ULL
#define WS_NEED_FALLBACK 10024000ULL

typedef float f32x4 __attribute__((ext_vector_type(4)));
typedef float f32x2 __attribute__((ext_vector_type(2)));
typedef unsigned long long u64;
typedef u64 u64x2 __attribute__((ext_vector_type(2)));

// ---------------- threefry2x32 (bit-exact JAX implementation) ----------------
__device__ __forceinline__ void tf2x32(uint32_t k0, uint32_t k1,
                                       uint32_t c0, uint32_t c1,
                                       uint32_t& o0, uint32_t& o1) {
  const uint32_t ks2 = k0 ^ k1 ^ 0x1BD11BDAu;
  uint32_t x0 = c0 + k0;
  uint32_t x1 = c1 + k1;
#define TF_RND(r) { x0 += x1; x1 = (x1 << (r)) | (x1 >> (32 - (r))); x1 ^= x0; }
  TF_RND(13) TF_RND(15) TF_RND(26) TF_RND(6)
  x0 += k1;  x1 += ks2 + 1u;
  TF_RND(17) TF_RND(29) TF_RND(16) TF_RND(24)
  x0 += ks2; x1 += k0 + 2u;
  TF_RND(13) TF_RND(15) TF_RND(26) TF_RND(6)
  x0 += k0;  x1 += k1 + 3u;
  TF_RND(17) TF_RND(29) TF_RND(16) TF_RND(24)
  x0 += k1;  x1 += ks2 + 4u;
  TF_RND(13) TF_RND(15) TF_RND(26) TF_RND(6)
  x0 += ks2; x1 += k0 + 5u;
#undef TF_RND
  o0 = x0; o1 = x1;
}

__device__ __forceinline__ int spike_value(int e) {
  uint32_t r0 = 0u, r1 = 42u;   // threefry_seed(42) = (0, 42)
  float S = 0.0f;
  int result = 63;
  for (int iter = 0; iter < 64; ++iter) {
    uint32_t n0, n1, s0, s1;
    tf2x32(r0, r1, 0u, 0u, n0, n1);
    tf2x32(r0, r1, 0u, 1u, s0, s1);
    r0 = n0; r1 = n1;
    uint32_t h0, h1;
    tf2x32(s0, s1, 0u, (uint32_t)e, h0, h1);
    const uint32_t bits = h0 ^ h1;
    const float u = __uint_as_float((bits >> 9) | 0x3f800000u) - 1.0f;
    S += logf(u);
    if (!(S > -1.0f)) { result = iter; break; }
  }
  return result;
}

__device__ __forceinline__ void load_nnz(int i,
                                         const float* __restrict__ wv, const int* __restrict__ rv,
                                         const int* __restrict__ cv,
                                         const float* __restrict__ wl, const int* __restrict__ rl,
                                         const int* __restrict__ cl,
                                         int& grow, int& col, float& w) {
  if (i < NNZV1) { grow = rv[i]; col = cv[i]; w = wv[i]; }
  else { const int j = i - NNZV1; grow = NV1 + rl[j]; col = cl[j]; w = wl[j]; }
}

// ==================== SORT PATH (3 kernels) =================================
// K1: padded spikes [600][12] + zero binCount
#define SB ((TLEN * 12 + 255) / 256)   // 29 blocks
__global__ void __launch_bounds__(256) k1_spikes(float* __restrict__ spikes_p,
                                                 uint32_t* __restrict__ binCount) {
  const int gid = blockIdx.x * 256 + threadIdx.x;
  if (gid < NB) binCount[gid] = 0u;
  if (gid < TLEN * 12) {
    const int row = gid / 12, u = gid - row * 12;
    spikes_p[gid] = (u < UU) ? (float)spike_value(row * UU + u) : 0.f;
  }
}

// K3: single-pass binning into fixed-capacity slots.
// R20: BBLK=1024, BPT=4 -> 4 blocks/CU (4 waves/SIMD) to hide the scattered
// load + LDS-atomic latency chain that made the 2-wave/SIMD version ~25 us.
__global__ void __launch_bounds__(256) k3_bin(const float* __restrict__ wv, const int* __restrict__ rv,
                                              const int* __restrict__ cv,
                                              const float* __restrict__ wl, const int* __restrict__ rl,
                                              const int* __restrict__ cl,
                                              uint32_t* __restrict__ binCount,
                                              u64* __restrict__ slots) {
  __shared__ uint32_t hist[256];
  __shared__ uint32_t cur[256];
  const int t = threadIdx.x;
  hist[t] = 0u;
  __syncthreads();
  const int base = blockIdx.x * (256 * BPT);
  u64 pk[BPT];
#pragma unroll
  for (int r = 0; r < BPT; ++r) {
    const int i = base + r * 256 + t;
    pk[r] = ~0ULL;
    if (i < NNZTOT) {
      int grow, col; float w;
      load_nnz(i, wv, rv, cv, wl, rl, cl, grow, col, w);
      pk[r] = ((u64)((uint32_t)grow | ((uint32_t)col << 18)) << 32) |
              (u64)__float_as_uint(w);
      atomicAdd(&hist[grow >> BINSHIFT], 1u);
    }
  }
  __syncthreads();
  if (t < NB) {
    const uint32_t h = hist[t];
    cur[t] = h ? atomicAdd(&binCount[t], h) : 0u;
  }
  __syncthreads();
#pragma unroll
  for (int r = 0; r < BPT; ++r) {
    if (pk[r] != ~0ULL) {
      const uint32_t rc = (uint32_t)(pk[r] >> 32);
      const int bin = (int)((rc & 0x3FFFFu) >> BINSHIFT);
      const uint32_t pos = atomicAdd(&cur[bin], 1u);
      if (pos < CAP) slots[(size_t)bin * CAP + pos] = pk[r];
    }
  }
}

// K5: fused accumulate + stream (R18 winner, unchanged). 512 threads per
// block, ONE block per 1024-row bin; single shared accumulate (paired 16B
// loads), lanes [0,256) stream t in [0,300), lanes [256,512) stream
// t in [300,600) — f32x4 nt stores, 4 rows/thread.
// LDS: acc 40 KB + spikes 28.8 KB = 68.8 KB -> 2 blocks/CU.
#define SROW 12
__global__ void __launch_bounds__(512) k5_fused(const u64* __restrict__ slots,
                                                const uint32_t* __restrict__ binCount,
                                                const float* __restrict__ spikes_p,
                                                float* __restrict__ out) {
  __shared__ float acc[BINROWS * UU];      // 40 KB
  __shared__ float s[TLEN * SROW];         // 28.8 KB
  const int tid = threadIdx.x;
  const int bin = blockIdx.x;              // 0..244
  const int row0 = bin << BINSHIFT;

  for (int i = tid; i < BINROWS * UU; i += 512) acc[i] = 0.f;
  {
    const f32x4* src = reinterpret_cast<const f32x4*>(spikes_p);
    f32x4* dst = reinterpret_cast<f32x4*>(s);
    for (int i = tid; i < TLEN * SROW / 4; i += 512) dst[i] = src[i];
  }
  __syncthreads();

  int cnt = (int)binCount[bin];
  if (cnt > CAP) cnt = CAP;
  const u64* sl = slots + (size_t)bin * CAP;
  for (int i = tid * 2; i < cnt; i += 1024) {
    if (i + 1 < cnt) {
      const u64x2 vv = *reinterpret_cast<const u64x2*>(&sl[i]);
#pragma unroll
      for (int q = 0; q < 2; ++q) {
        const u64 v = vv[q];
        const uint32_t rc = (uint32_t)(v >> 32);
        atomicAdd(&acc[((int)(rc & 0x3FFFFu) - row0) * UU + (int)(rc >> 18)],
                  __uint_as_float((uint32_t)v));
      }
    } else {
      const u64 v = sl[i];
      const uint32_t rc = (uint32_t)(v >> 32);
      atomicAdd(&acc[((int)(rc & 0x3FFFFu) - row0) * UU + (int)(rc >> 18)],
                __uint_as_float((uint32_t)v));
    }
  }
  __syncthreads();

  const int t8   = tid & 255;              // row-quad index within bin
  const int half = tid >> 8;               // which t-half this thread streams
  const int n = row0 + t8 * 4;             // 4 consecutive rows per thread
  if (n >= NTOT) return;                   // tail bin: 144 rows
  float w[4][UU];
#pragma unroll
  for (int r = 0; r < 4; ++r)
#pragma unroll
    for (int u = 0; u < UU; ++u)
      w[r][u] = acc[(t8 * 4 + r) * UU + u];

  const int tt0 = half * THALF;
  float* op = out + (size_t)tt0 * NTOT + n;
  for (int tl = 0; tl < THALF; ++tl) {
    const int trow = tt0 + tl;
    const f32x4 sA = *reinterpret_cast<const f32x4*>(&s[trow * SROW]);
    const f32x4 sB = *reinterpret_cast<const f32x4*>(&s[trow * SROW + 4]);
    const f32x2 sC = *reinterpret_cast<const f32x2*>(&s[trow * SROW + 8]);
    f32x4 a;
#pragma unroll
    for (int r = 0; r < 4; ++r) {
      float x = sA.x * w[r][0];
      x = fmaf(sA.y, w[r][1], x);
      x = fmaf(sA.z, w[r][2], x);
      x = fmaf(sA.w, w[r][3], x);
      x = fmaf(sB.x, w[r][4], x);
      x = fmaf(sB.y, w[r][5], x);
      x = fmaf(sB.z, w[r][6], x);
      x = fmaf(sB.w, w[r][7], x);
      x = fmaf(sC.x, w[r][8], x);
      x = fmaf(sC.y, w[r][9], x);
      a[r] = x;
    }
    __builtin_nontemporal_store(a, reinterpret_cast<f32x4*>(op));
    op += NTOT;
  }
}

// ==================== FALLBACK PATH (R6, proven) ============================
#define WZ4 (NTOT * UU / 4)
#define ZB  ((WZ4 + 255) / 256)
#define SBF ((NELEM + 255) / 256)
__global__ void __launch_bounds__(256) init_kernel(f32x4* __restrict__ W4,
                                                   float* __restrict__ spikes) {
  const int b = blockIdx.x;
  if (b < ZB) {
    const int i = b * 256 + threadIdx.x;
    if (i < WZ4) W4[i] = (f32x4)(0.f);
    return;
  }
  const int e = (b - ZB) * 256 + threadIdx.x;
  if (e >= NELEM) return;
  spikes[e] = (float)spike_value(e);
}

__global__ void scatter_kernel(const float* __restrict__ w_v1,
                               const int* __restrict__ rows_v1,
                               const int* __restrict__ cols_v1,
                               const float* __restrict__ w_lm,
                               const int* __restrict__ rows_lm,
                               const int* __restrict__ cols_lm,
                               float* __restrict__ WT) {
  const int i = blockIdx.x * blockDim.x + threadIdx.x;
  if (i >= NNZTOT) return;
  if (i < NNZV1) {
    atomicAdd(&WT[(size_t)cols_v1[i] * NTOT + rows_v1[i]], w_v1[i]);
  } else {
    const int j = i - NNZV1;
    atomicAdd(&WT[(size_t)cols_lm[j] * NTOT + NV1 + rows_lm[j]], w_lm[j]);
  }
}

#define TTILE 75
#define NT4 (NTOT / 4)
__global__ void __launch_bounds__(256, 8) out_kernel(const float* __restrict__ WT,
                                                     const float* __restrict__ spikes,
                                                     float* __restrict__ out) {
  __shared__ float s[TTILE * SROW];
  const int t0 = blockIdx.y * TTILE;
  for (int i = threadIdx.x; i < TTILE * SROW; i += 256) {
    const int row = i / SROW, u = i - row * SROW;
    s[i] = (u < UU) ? spikes[(t0 + row) * UU + u] : 0.f;
  }
  __syncthreads();

  const int n4 = blockIdx.x * 256 + threadIdx.x;
  if (n4 >= NT4) return;
  const int n = n4 * 4;

  f32x4 w[UU];
#pragma unroll
  for (int u = 0; u < UU; ++u)
    w[u] = *reinterpret_cast<const f32x4*>(&WT[(size_t)u * NTOT + n]);

  float* op = &out[(size_t)t0 * NTOT + n];
  for (int t = 0; t < TTILE; ++t) {
    const f32x4 sA = *reinterpret_cast<const f32x4*>(&s[t * SROW]);
    const f32x4 sB = *reinterpret_cast<const f32x4*>(&s[t * SROW + 4]);
    const f32x2 sC = *reinterpret_cast<const f32x2*>(&s[t * SROW + 8]);
    f32x4 acc = sA.x * w[0];
    acc += sA.y * w[1];
    acc += sA.z * w[2];
    acc += sA.w * w[3];
    acc += sB.x * w[4];
    acc += sB.y * w[5];
    acc += sB.z * w[6];
    acc += sB.w * w[7];
    acc += sC.x * w[8];
    acc += sC.y * w[9];
    __builtin_nontemporal_store(acc, reinterpret_cast<f32x4*>(op));
    op += NTOT;
  }
}

extern "C" void kernel_launch(void* const* d_in, const int* in_sizes, int n_in,
                              void* d_out, int out_size, void* d_ws, size_t ws_size,
                              hipStream_t stream) {
  const float* w_v1    = (const float*)d_in[1];
  const int*   rows_v1 = (const int*)d_in[2];
  const int*   cols_v1 = (const int*)d_in[3];
  const float* w_lm    = (const float*)d_in[4];
  const int*   rows_lm = (const int*)d_in[5];
  const int*   cols_lm = (const int*)d_in[6];
  float* out = (float*)d_out;

  char* ws = (char*)d_ws;

  if (ws_size >= WS_NEED_SORT) {
    u64*      slots    = (u64*)(ws + SLOTS_OFF);
    float*    spikes_p = (float*)(ws + SPIKES2_OFF);
    uint32_t* binCount = (uint32_t*)(ws + BINCNT_OFF);
    k1_spikes<<<SB, 256, 0, stream>>>(spikes_p, binCount);
    k3_bin<<<BBLK, 256, 0, stream>>>(w_v1, rows_v1, cols_v1,
                                     w_lm, rows_lm, cols_lm, binCount, slots);
    k5_fused<<<NB, 512, 0, stream>>>(slots, binCount, spikes_p, out);
  } else if (ws_size >= WS_NEED_FALLBACK) {
    float* WT     = (float*)(ws + WT_OFF);
    float* spikes = (float*)(ws + SPIKES_OFF);
    init_kernel<<<ZB + SBF, 256, 0, stream>>>((f32x4*)WT, spikes);
    scatter_kernel<<<(NNZTOT + 255) / 256, 256, 0, stream>>>(w_v1, rows_v1, cols_v1,
                                                             w_lm, rows_lm, cols_lm, WT);
    dim3 grid((NT4 + 255) / 256, TLEN / TTILE);
    out_kernel<<<grid, 256, 0, stream>>>(WT, spikes, out);
  }
}

// Round 21
// 151.289 us; speedup vs baseline: 1.0430x; 1.0430x over previous
//
#include <hip/hip_runtime.h>
#include <stdint.h>

// Problem constants (match reference)
#define NV1 200000
#define NLM 50000
#define NTOT 250000        // NV1 + NLM
#define TLEN 600
#define UU 10
#define NNZV1 800000
#define NNZLM 200000
#define NNZTOT (NNZV1 + NNZLM)
#define NELEM (TLEN * UU)  // 6000 poisson elements

// Binning parameters (1024-row bins) — R18 best configuration
#define BINSHIFT 10
#define BINROWS 1024
#define NB 245                   // ceil(250000/1024)
#define CAP 4608                 // mean 4096, sigma ~64 -> +8 sigma
#define BBLK 512                 // binning blocks (2/CU) — measured optimum
#define BPT 8                    // 512*256*8 = 1,048,576 >= 1e6

#define THALF (TLEN / 2)         // 300

// Sort-path workspace offsets
#define SLOTS_OFF   0ULL                  // 245*4608*8 = 9,031,680 B
#define SPIKES2_OFF 9031680ULL            // 600*12*4 = 28,800 B (padded rows)
#define BINCNT_OFF  9060480ULL            // 245*4
#define WS_NEED_SORT 9061460ULL
// Fallback offsets (R6 path)
#define WT_OFF      0ULL
#define SPIKES_OFF  10000000ULL
#define WS_NEED_FALLBACK 10024000ULL

typedef float f32x4 __attribute__((ext_vector_type(4)));
typedef float f32x2 __attribute__((ext_vector_type(2)));
typedef unsigned long long u64;
typedef u64 u64x2 __attribute__((ext_vector_type(2)));

// ---------------- threefry2x32 (bit-exact JAX implementation) ----------------
__device__ __forceinline__ void tf2x32(uint32_t k0, uint32_t k1,
                                       uint32_t c0, uint32_t c1,
                                       uint32_t& o0, uint32_t& o1) {
  const uint32_t ks2 = k0 ^ k1 ^ 0x1BD11BDAu;
  uint32_t x0 = c0 + k0;
  uint32_t x1 = c1 + k1;
#define TF_RND(r) { x0 += x1; x1 = (x1 << (r)) | (x1 >> (32 - (r))); x1 ^= x0; }
  TF_RND(13) TF_RND(15) TF_RND(26) TF_RND(6)
  x0 += k1;  x1 += ks2 + 1u;
  TF_RND(17) TF_RND(29) TF_RND(16) TF_RND(24)
  x0 += ks2; x1 += k0 + 2u;
  TF_RND(13) TF_RND(15) TF_RND(26) TF_RND(6)
  x0 += k0;  x1 += k1 + 3u;
  TF_RND(17) TF_RND(29) TF_RND(16) TF_RND(24)
  x0 += k1;  x1 += ks2 + 4u;
  TF_RND(13) TF_RND(15) TF_RND(26) TF_RND(6)
  x0 += ks2; x1 += k0 + 5u;
#undef TF_RND
  o0 = x0; o1 = x1;
}

__device__ __forceinline__ int spike_value(int e) {
  uint32_t r0 = 0u, r1 = 42u;   // threefry_seed(42) = (0, 42)
  float S = 0.0f;
  int result = 63;
  for (int iter = 0; iter < 64; ++iter) {
    uint32_t n0, n1, s0, s1;
    tf2x32(r0, r1, 0u, 0u, n0, n1);
    tf2x32(r0, r1, 0u, 1u, s0, s1);
    r0 = n0; r1 = n1;
    uint32_t h0, h1;
    tf2x32(s0, s1, 0u, (uint32_t)e, h0, h1);
    const uint32_t bits = h0 ^ h1;
    const float u = __uint_as_float((bits >> 9) | 0x3f800000u) - 1.0f;
    S += logf(u);
    if (!(S > -1.0f)) { result = iter; break; }
  }
  return result;
}

__device__ __forceinline__ void load_nnz(int i,
                                         const float* __restrict__ wv, const int* __restrict__ rv,
                                         const int* __restrict__ cv,
                                         const float* __restrict__ wl, const int* __restrict__ rl,
                                         const int* __restrict__ cl,
                                         int& grow, int& col, float& w) {
  if (i < NNZV1) { grow = rv[i]; col = cv[i]; w = wv[i]; }
  else { const int j = i - NNZV1; grow = NV1 + rl[j]; col = cl[j]; w = wl[j]; }
}

// ==================== SORT PATH (3 kernels) =================================
// K1: padded spikes [600][12] + zero binCount
#define SB ((TLEN * 12 + 255) / 256)   // 29 blocks
__global__ void __launch_bounds__(256) k1_spikes(float* __restrict__ spikes_p,
                                                 uint32_t* __restrict__ binCount) {
  const int gid = blockIdx.x * 256 + threadIdx.x;
  if (gid < NB) binCount[gid] = 0u;
  if (gid < TLEN * 12) {
    const int row = gid / 12, u = gid - row * 12;
    spikes_p[gid] = (u < UU) ? (float)spike_value(row * UU + u) : 0.f;
  }
}

// K3: single-pass binning into fixed-capacity slots.
__global__ void __launch_bounds__(256) k3_bin(const float* __restrict__ wv, const int* __restrict__ rv,
                                              const int* __restrict__ cv,
                                              const float* __restrict__ wl, const int* __restrict__ rl,
                                              const int* __restrict__ cl,
                                              uint32_t* __restrict__ binCount,
                                              u64* __restrict__ slots) {
  __shared__ uint32_t hist[256];
  __shared__ uint32_t cur[256];
  const int t = threadIdx.x;
  hist[t] = 0u;
  __syncthreads();
  const int base = blockIdx.x * (256 * BPT);
  u64 pk[BPT];
#pragma unroll
  for (int r = 0; r < BPT; ++r) {
    const int i = base + r * 256 + t;
    pk[r] = ~0ULL;
    if (i < NNZTOT) {
      int grow, col; float w;
      load_nnz(i, wv, rv, cv, wl, rl, cl, grow, col, w);
      pk[r] = ((u64)((uint32_t)grow | ((uint32_t)col << 18)) << 32) |
              (u64)__float_as_uint(w);
      atomicAdd(&hist[grow >> BINSHIFT], 1u);
    }
  }
  __syncthreads();
  if (t < NB) {
    const uint32_t h = hist[t];
    cur[t] = h ? atomicAdd(&binCount[t], h) : 0u;
  }
  __syncthreads();
#pragma unroll
  for (int r = 0; r < BPT; ++r) {
    if (pk[r] != ~0ULL) {
      const uint32_t rc = (uint32_t)(pk[r] >> 32);
      const int bin = (int)((rc & 0x3FFFFu) >> BINSHIFT);
      const uint32_t pos = atomicAdd(&cur[bin], 1u);
      if (pos < CAP) slots[(size_t)bin * CAP + pos] = pk[r];
    }
  }
}

// K5: fused accumulate + stream, 512 threads per block, ONE block per bin.
// All 512 threads share a single accumulate pass (no duplication, paired 16B
// loads), then lanes [0,256) stream t in [0,300) and lanes [256,512) stream
// t in [300,600) — f32x4 nt stores, 4 rows/thread.
// LDS: acc 40 KB + spikes 28.8 KB = 68.8 KB -> 2 blocks/CU (16 waves/CU).
#define SROW 12
__global__ void __launch_bounds__(512) k5_fused(const u64* __restrict__ slots,
                                                const uint32_t* __restrict__ binCount,
                                                const float* __restrict__ spikes_p,
                                                float* __restrict__ out) {
  __shared__ float acc[BINROWS * UU];      // 40 KB
  __shared__ float s[TLEN * SROW];         // 28.8 KB
  const int tid = threadIdx.x;
  const int bin = blockIdx.x;              // 0..244
  const int row0 = bin << BINSHIFT;

  for (int i = tid; i < BINROWS * UU; i += 512) acc[i] = 0.f;
  {
    const f32x4* src = reinterpret_cast<const f32x4*>(spikes_p);
    f32x4* dst = reinterpret_cast<f32x4*>(s);
    for (int i = tid; i < TLEN * SROW / 4; i += 512) dst[i] = src[i];
  }
  __syncthreads();

  int cnt = (int)binCount[bin];
  if (cnt > CAP) cnt = CAP;
  const u64* sl = slots + (size_t)bin * CAP;
  for (int i = tid * 2; i < cnt; i += 1024) {
    if (i + 1 < cnt) {
      const u64x2 vv = *reinterpret_cast<const u64x2*>(&sl[i]);
#pragma unroll
      for (int q = 0; q < 2; ++q) {
        const u64 v = vv[q];
        const uint32_t rc = (uint32_t)(v >> 32);
        atomicAdd(&acc[((int)(rc & 0x3FFFFu) - row0) * UU + (int)(rc >> 18)],
                  __uint_as_float((uint32_t)v));
      }
    } else {
      const u64 v = sl[i];
      const uint32_t rc = (uint32_t)(v >> 32);
      atomicAdd(&acc[((int)(rc & 0x3FFFFu) - row0) * UU + (int)(rc >> 18)],
                __uint_as_float((uint32_t)v));
    }
  }
  __syncthreads();

  const int t8   = tid & 255;              // row-quad index within bin
  const int half = tid >> 8;               // which t-half this thread streams
  const int n = row0 + t8 * 4;             // 4 consecutive rows per thread
  if (n >= NTOT) return;                   // tail bin: 144 rows
  float w[4][UU];
#pragma unroll
  for (int r = 0; r < 4; ++r)
#pragma unroll
    for (int u = 0; u < UU; ++u)
      w[r][u] = acc[(t8 * 4 + r) * UU + u];

  const int tt0 = half * THALF;
  float* op = out + (size_t)tt0 * NTOT + n;
  for (int tl = 0; tl < THALF; ++tl) {
    const int trow = tt0 + tl;
    const f32x4 sA = *reinterpret_cast<const f32x4*>(&s[trow * SROW]);
    const f32x4 sB = *reinterpret_cast<const f32x4*>(&s[trow * SROW + 4]);
    const f32x2 sC = *reinterpret_cast<const f32x2*>(&s[trow * SROW + 8]);
    f32x4 a;
#pragma unroll
    for (int r = 0; r < 4; ++r) {
      float x = sA.x * w[r][0];
      x = fmaf(sA.y, w[r][1], x);
      x = fmaf(sA.z, w[r][2], x);
      x = fmaf(sA.w, w[r][3], x);
      x = fmaf(sB.x, w[r][4], x);
      x = fmaf(sB.y, w[r][5], x);
      x = fmaf(sB.z, w[r][6], x);
      x = fmaf(sB.w, w[r][7], x);
      x = fmaf(sC.x, w[r][8], x);
      x = fmaf(sC.y, w[r][9], x);
      a[r] = x;
    }
    __builtin_nontemporal_store(a, reinterpret_cast<f32x4*>(op));
    op += NTOT;
  }
}

// ==================== FALLBACK PATH (R6, proven) ============================
#define WZ4 (NTOT * UU / 4)
#define ZB  ((WZ4 + 255) / 256)
#define SBF ((NELEM + 255) / 256)
__global__ void __launch_bounds__(256) init_kernel(f32x4* __restrict__ W4,
                                                   float* __restrict__ spikes) {
  const int b = blockIdx.x;
  if (b < ZB) {
    const int i = b * 256 + threadIdx.x;
    if (i < WZ4) W4[i] = (f32x4)(0.f);
    return;
  }
  const int e = (b - ZB) * 256 + threadIdx.x;
  if (e >= NELEM) return;
  spikes[e] = (float)spike_value(e);
}

__global__ void scatter_kernel(const float* __restrict__ w_v1,
                               const int* __restrict__ rows_v1,
                               const int* __restrict__ cols_v1,
                               const float* __restrict__ w_lm,
                               const int* __restrict__ rows_lm,
                               const int* __restrict__ cols_lm,
                               float* __restrict__ WT) {
  const int i = blockIdx.x * blockDim.x + threadIdx.x;
  if (i >= NNZTOT) return;
  if (i < NNZV1) {
    atomicAdd(&WT[(size_t)cols_v1[i] * NTOT + rows_v1[i]], w_v1[i]);
  } else {
    const int j = i - NNZV1;
    atomicAdd(&WT[(size_t)cols_lm[j] * NTOT + NV1 + rows_lm[j]], w_lm[j]);
  }
}

#define TTILE 75
#define NT4 (NTOT / 4)
__global__ void __launch_bounds__(256, 8) out_kernel(const float* __restrict__ WT,
                                                     const float* __restrict__ spikes,
                                                     float* __restrict__ out) {
  __shared__ float s[TTILE * SROW];
  const int t0 = blockIdx.y * TTILE;
  for (int i = threadIdx.x; i < TTILE * SROW; i += 256) {
    const int row = i / SROW, u = i - row * SROW;
    s[i] = (u < UU) ? spikes[(t0 + row) * UU + u] : 0.f;
  }
  __syncthreads();

  const int n4 = blockIdx.x * 256 + threadIdx.x;
  if (n4 >= NT4) return;
  const int n = n4 * 4;

  f32x4 w[UU];
#pragma unroll
  for (int u = 0; u < UU; ++u)
    w[u] = *reinterpret_cast<const f32x4*>(&WT[(size_t)u * NTOT + n]);

  float* op = &out[(size_t)t0 * NTOT + n];
  for (int t = 0; t < TTILE; ++t) {
    const f32x4 sA = *reinterpret_cast<const f32x4*>(&s[t * SROW]);
    const f32x4 sB = *reinterpret_cast<const f32x4*>(&s[t * SROW + 4]);
    const f32x2 sC = *reinterpret_cast<const f32x2*>(&s[t * SROW + 8]);
    f32x4 acc = sA.x * w[0];
    acc += sA.y * w[1];
    acc += sA.z * w[2];
    acc += sA.w * w[3];
    acc += sB.x * w[4];
    acc += sB.y * w[5];
    acc += sB.z * w[6];
    acc += sB.w * w[7];
    acc += sC.x * w[8];
    acc += sC.y * w[9];
    __builtin_nontemporal_store(acc, reinterpret_cast<f32x4*>(op));
    op += NTOT;
  }
}

extern "C" void kernel_launch(void* const* d_in, const int* in_sizes, int n_in,
                              void* d_out, int out_size, void* d_ws, size_t ws_size,
                              hipStream_t stream) {
  const float* w_v1    = (const float*)d_in[1];
  const int*   rows_v1 = (const int*)d_in[2];
  const int*   cols_v1 = (const int*)d_in[3];
  const float* w_lm    = (const float*)d_in[4];
  const int*   rows_lm = (const int*)d_in[5];
  const int*   cols_lm = (const int*)d_in[6];
  float* out = (float*)d_out;

  char* ws = (char*)d_ws;

  if (ws_size >= WS_NEED_SORT) {
    u64*      slots    = (u64*)(ws + SLOTS_OFF);
    float*    spikes_p = (float*)(ws + SPIKES2_OFF);
    uint32_t* binCount = (uint32_t*)(ws + BINCNT_OFF);
    k1_spikes<<<SB, 256, 0, stream>>>(spikes_p, binCount);
    k3_bin<<<BBLK, 256, 0, stream>>>(w_v1, rows_v1, cols_v1,
                                     w_lm, rows_lm, cols_lm, binCount, slots);
    k5_fused<<<NB, 512, 0, stream>>>(slots, binCount, spikes_p, out);
  } else if (ws_size >= WS_NEED_FALLBACK) {
    float* WT     = (float*)(ws + WT_OFF);
    float* spikes = (float*)(ws + SPIKES_OFF);
    init_kernel<<<ZB + SBF, 256, 0, stream>>>((f32x4*)WT, spikes);
    scatter_kernel<<<(NNZTOT + 255) / 256, 256, 0, stream>>>(w_v1, rows_v1, cols_v1,
                                                             w_lm, rows_lm, cols_lm, WT);
    dim3 grid((NT4 + 255) / 256, TLEN / TTILE);
    out_kernel<<<grid, 256, 0, stream>>>(WT, spikes, out);
  }
}